// Round 5
// baseline (724.394 us; speedup 1.0000x reference)
//
#include <hip/hip_runtime.h>

#define N_NODES 25000
#define N_EDGES 400000

// ---------------- fast transcendentals (fp32, ~2ulp) ----------------
__device__ __forceinline__ float fast_sigmoid(float x) {
    return __builtin_amdgcn_rcpf(1.0f + __expf(-x));
}
__device__ __forceinline__ float fast_tanh(float x) {
    return 1.0f - 2.0f * __builtin_amdgcn_rcpf(__expf(2.0f * x) + 1.0f);
}

// DPP cross-lane within 16-lane rows (pure VALU, no DS). All ops are
// XOR-type (self-inverse) so hardware shift-direction ambiguity is moot:
//   0xB1  = quad_perm [1,0,3,2]  -> lane j gets j^1
//   0x4E  = quad_perm [2,3,0,1]  -> lane j gets j^2
//   0x141 = row_half_mirror      -> lane j gets j^7
//   0x128 = row_ror:8            -> lane j gets j^8  (rotate by half-row)
#define DPPF(x, ctrl) __int_as_float(__builtin_amdgcn_update_dpp( \
        __float_as_int(x), __float_as_int(x), (ctrl), 0xF, 0xF, false))

// Broadcast lane l (0..15) of the 16-lane group to all 16 (ds_swizzle, or-mask)
#define BC16(x, l) __int_as_float(__builtin_amdgcn_ds_swizzle(__float_as_int(x), ((l) << 5) | 0x10))

// ---------------- K1: hidden0 = nf @ W_init + b_init ; copy; zero cnts --------
__global__ void __launch_bounds__(256) k_init(
        const float* __restrict__ nf, const float* __restrict__ Wini,
        const float* __restrict__ bini,
        float* __restrict__ hidden0, float* __restrict__ hid,
        int* __restrict__ cnt_s, int* __restrict__ cnt_r)
{
    int gtid = blockIdx.x * 256 + threadIdx.x;
    if (gtid <= N_NODES) { cnt_s[gtid] = 0; cnt_r[gtid] = 0; }
    int node = gtid >> 4;
    int j = gtid & 15;
    if (node >= N_NODES) return;

    const float4* nf4 = (const float4*)(nf + node * 32);
    float acc = bini[j];
#pragma unroll
    for (int g = 0; g < 8; ++g) {
        float4 v = nf4[g];
        acc = fmaf(v.x, Wini[(g*4+0)*16 + j], acc);
        acc = fmaf(v.y, Wini[(g*4+1)*16 + j], acc);
        acc = fmaf(v.z, Wini[(g*4+2)*16 + j], acc);
        acc = fmaf(v.w, Wini[(g*4+3)*16 + j], acc);
    }
    hidden0[node*16 + j] = acc;
    hid[node*16 + j] = acc;
}

// ---------------- CSR build ----------------
__global__ void __launch_bounds__(256) k_hist(const int* __restrict__ send,
        const int* __restrict__ recv,
        int* __restrict__ cnt_s, int* __restrict__ cnt_r)
{
    int e = blockIdx.x * 256 + threadIdx.x;
    if (e < N_EDGES) {
        atomicAdd(&cnt_s[send[e]], 1);
        atomicAdd(&cnt_r[recv[e]], 1);
    }
}

// grid=2: block 0 scans sender counts, block 1 scans receiver counts
__global__ void __launch_bounds__(1024) k_scan(
        const int* __restrict__ cnt_s, const int* __restrict__ cnt_r,
        int* __restrict__ srow, int* __restrict__ scur,
        int* __restrict__ rrow, int* __restrict__ rcur,
        float* __restrict__ out)
{
    const int* cnt = (blockIdx.x == 0) ? cnt_s : cnt_r;
    int* row = (blockIdx.x == 0) ? srow : rrow;
    int* cur = (blockIdx.x == 0) ? scur : rcur;

    __shared__ int sums[1024];
    int t = threadIdx.x;
    const int CH = (N_NODES + 1023) / 1024 + 1;   // 25 -> covers 25600
    int base = t * CH;
    int s = 0;
    for (int i = 0; i < CH; ++i) {
        int idx = base + i;
        if (idx < N_NODES) s += cnt[idx];
    }
    sums[t] = s;
    __syncthreads();
    for (int off = 1; off < 1024; off <<= 1) {
        int add = (t >= off) ? sums[t - off] : 0;
        __syncthreads();
        sums[t] += add;
        __syncthreads();
    }
    int run = sums[t] - s;
    for (int i = 0; i < CH; ++i) {
        int idx = base + i;
        if (idx < N_NODES) {
            row[idx] = run;
            cur[idx] = run;
            run += cnt[idx];
        }
    }
    if (t == 0) {
        row[N_NODES] = N_EDGES;
        if (blockIdx.x == 0) out[0] = 0.0f;
    }
}

// eids[sp]=e ; gpos[rp]=sp ; optionally efp[sp,:]=ef[e,:]
__global__ void __launch_bounds__(256) k_scatter(const int* __restrict__ send,
        const int* __restrict__ recv,
        int* __restrict__ scur, int* __restrict__ rcur,
        int* __restrict__ eids, int* __restrict__ gpos,
        const float* __restrict__ ef, float* __restrict__ efp)
{
    int e = blockIdx.x * 256 + threadIdx.x;
    if (e < N_EDGES) {
        int s = send[e];
        int r = recv[e];
        int sp = atomicAdd(&scur[s], 1);
        int rp = atomicAdd(&rcur[r], 1);
        eids[sp] = e;
        gpos[rp] = sp;
        if (efp) {
            const float4* src = (const float4*)(ef + (size_t)e * 16);
            float4* dst = (float4*)(efp + (size_t)sp * 16);
            dst[0] = src[0]; dst[1] = src[1]; dst[2] = src[2]; dst[3] = src[3];
        }
    }
}

// ---------------- per-sender q computation helper ----------------
__device__ __forceinline__ void load_q(const float* __restrict__ hid, int s, int m,
        const float* __restrict__ We, const float* __restrict__ be,
        float* __restrict__ q, float& qb)
{
    float h[16];
    {
        const float4* h4 = (const float4*)(hid + s*16);
        float4 a = h4[0], b = h4[1], c = h4[2], d = h4[3];
        h[0]=a.x;  h[1]=a.y;  h[2]=a.z;  h[3]=a.w;
        h[4]=b.x;  h[5]=b.y;  h[6]=b.z;  h[7]=b.w;
        h[8]=c.x;  h[9]=c.y;  h[10]=c.z; h[11]=c.w;
        h[12]=d.x; h[13]=d.y; h[14]=d.z; h[15]=d.w;
    }
#pragma unroll
    for (int f = 0; f < 16; ++f) {
        const float4* wf = (const float4*)(We + f*256 + m*16);
        float4 a = wf[0], b = wf[1], c = wf[2], d = wf[3];
        float acc;
        acc  = a.x*h[0]  + a.y*h[1]  + a.z*h[2]  + a.w*h[3];
        acc += b.x*h[4]  + b.y*h[5]  + b.z*h[6]  + b.w*h[7];
        acc += c.x*h[8]  + c.y*h[9]  + c.z*h[10] + c.w*h[11];
        acc += d.x*h[12] + d.y*h[13] + d.z*h[14] + d.w*h[15];
        q[f] = acc;
    }
    {
        const float4* bf = (const float4*)(be + m*16);
        float4 a = bf[0], b = bf[1], c = bf[2], d = bf[3];
        qb  = a.x*h[0]  + a.y*h[1]  + a.z*h[2]  + a.w*h[3];
        qb += b.x*h[4]  + b.y*h[5]  + b.z*h[6]  + b.w*h[7];
        qb += c.x*h[8]  + c.y*h[9]  + c.z*h[10] + c.w*h[11];
        qb += d.x*h[12] + d.y*h[13] + d.z*h[14] + d.w*h[15];
    }
}

__device__ __forceinline__ float edge_dot(float4 e0, float4 e1, float4 e2, float4 e3,
        const float* __restrict__ q, float qb)
{
    float a = qb;
    a = fmaf(e0.x, q[0],  a);
    a = fmaf(e0.y, q[1],  a);
    a = fmaf(e0.z, q[2],  a);
    a = fmaf(e0.w, q[3],  a);
    a = fmaf(e1.x, q[4],  a);
    a = fmaf(e1.y, q[5],  a);
    a = fmaf(e1.z, q[6],  a);
    a = fmaf(e1.w, q[7],  a);
    a = fmaf(e2.x, q[8],  a);
    a = fmaf(e2.y, q[9],  a);
    a = fmaf(e2.z, q[10], a);
    a = fmaf(e2.w, q[11], a);
    a = fmaf(e3.x, q[12], a);
    a = fmaf(e3.y, q[13], a);
    a = fmaf(e3.z, q[14], a);
    a = fmaf(e3.w, q[15], a);
    return a;
}

// ---------------- K3: messages — ONE WAVE PER SENDER ----------------
// 64 lanes = 4 sub-groups of 16; sub-group `sub` handles edges beg+sub,
// beg+sub+4, ... (4 edges in flight; efp reads & emsg writes are 256B
// contiguous per wave instruction). q computed redundantly per sub-group.
// 25000 waves -> ~24 waves/SIMD available: latency well hidden.
__global__ void __launch_bounds__(256) k_msg(
        const float* __restrict__ hid, const float* __restrict__ efp,
        const float* __restrict__ We, const float* __restrict__ be,
        const int* __restrict__ srow, float* __restrict__ emsg)
{
    int gtid = blockIdx.x * 256 + threadIdx.x;
    int s = gtid >> 6;              // one wave per sender
    if (s >= N_NODES) return;
    int lane = threadIdx.x & 63;
    int m = lane & 15;
    int sub = lane >> 4;

    float q[16], qb;
    load_q(hid, s, m, We, be, q, qb);

    int beg = srow[s];
    int end = srow[s + 1];
    for (int i = beg + sub; i < end; i += 4) {
        const float4* e4 = (const float4*)(efp + (size_t)i*16);
        float4 e0 = e4[0], e1 = e4[1], e2 = e4[2], e3 = e4[3];
        emsg[(size_t)i*16 + m] = edge_dot(e0, e1, e2, e3, q, qb);
    }
}

// ---------------- K4: gather segment-sum + GRU (T=32), in-place ----------
// group = node n (16 lanes, DPP-row aligned), lane j = GRU unit j.
// h cross-lane via XOR-type DPP chain (VALU only, no DS):
// step masks {1,2,1,7,1,2,1,8,1,2,1,7,1,2,1}, prefixes visit all j^1..j^15.
__global__ void __launch_bounds__(256) k_gru(
        float* __restrict__ hid, const float* __restrict__ emsg,
        const int* __restrict__ rrow, const int* __restrict__ gpos,
        const float* __restrict__ Wi, const float* __restrict__ Wh,
        const float* __restrict__ bi, const float* __restrict__ bh)
{
    int gtid = blockIdx.x * 256 + threadIdx.x;
    int node = gtid >> 4;
    int j = gtid & 15;
    if (node >= N_NODES) return;

    // prefix-XOR order of the DPP chain
    const int P[16] = {0,1,3,2,5,4,6,7,15,14,12,13,10,11,9,8};
    float Wz[16], Wr[16], Wc[16];
#pragma unroll
    for (int k = 0; k < 16; ++k) {
        int l = j ^ P[k];
        Wz[k] = Wh[l*48 + j];
        Wr[k] = Wh[l*48 + 16 + j];
        Wc[k] = Wh[l*48 + 32 + j];
    }
    float Wiz = Wi[j], Wir = Wi[16+j], Wih = Wi[32+j];
    float cz   = bi[j] + bh[j];
    float cr   = bi[16+j] + bh[16+j];
    float bih_ = bi[32+j];
    float bhh_ = bh[32+j];

    // segment sum via gather (4 independent loads in flight)
    float msum = 0.0f;
    {
        int beg = rrow[node];
        int end = rrow[node + 1];
        int p = beg;
        for (; p + 3 < end; p += 4) {
            int s0 = gpos[p], s1 = gpos[p+1], s2 = gpos[p+2], s3 = gpos[p+3];
            float v0 = emsg[(size_t)s0*16 + j];
            float v1 = emsg[(size_t)s1*16 + j];
            float v2 = emsg[(size_t)s2*16 + j];
            float v3 = emsg[(size_t)s3*16 + j];
            msum += (v0 + v1) + (v2 + v3);
        }
        for (; p < end; ++p)
            msum += emsg[(size_t)gpos[p]*16 + j];
    }

    float x[16];
    {
        const float4* a4 = (const float4*)(hid + node * 16);
#pragma unroll
        for (int g = 0; g < 4; ++g) {
            float4 v = a4[g];
            x[g*4+0]=v.x; x[g*4+1]=v.y; x[g*4+2]=v.z; x[g*4+3]=v.w;
        }
    }

    float hn = 0.0f;

#define DSTEP(k, ctrl) { v = DPPF(v, ctrl); \
        az = fmaf(v, Wz[k], az); ar = fmaf(v, Wr[k], ar); ac = fmaf(v, Wc[k], ac); }

#define GRU_STEP(XV) { float xv = (XV); \
        float az = fmaf(xv, Wiz, cz); \
        float ar = fmaf(xv, Wir, cr); \
        float ac = bhh_; \
        float v = hn; \
        az = fmaf(v, Wz[0], az); \
        ar = fmaf(v, Wr[0], ar); \
        ac = fmaf(v, Wc[0], ac); \
        DSTEP(1, 0xB1)  DSTEP(2, 0x4E)  DSTEP(3, 0xB1)  DSTEP(4, 0x141) \
        DSTEP(5, 0xB1)  DSTEP(6, 0x4E)  DSTEP(7, 0xB1)  DSTEP(8, 0x128) \
        DSTEP(9, 0xB1)  DSTEP(10, 0x4E) DSTEP(11, 0xB1) DSTEP(12, 0x141) \
        DSTEP(13, 0xB1) DSTEP(14, 0x4E) DSTEP(15, 0xB1) \
        float zg  = fast_sigmoid(az); \
        float rg  = fast_sigmoid(ar); \
        float hc = fast_tanh(fmaf(xv, Wih, bih_) + rg * ac); \
        hn = fmaf(zg, hn - hc, hc); }

    GRU_STEP(x[0])  GRU_STEP(x[1])  GRU_STEP(x[2])  GRU_STEP(x[3])
    GRU_STEP(x[4])  GRU_STEP(x[5])  GRU_STEP(x[6])  GRU_STEP(x[7])
    GRU_STEP(x[8])  GRU_STEP(x[9])  GRU_STEP(x[10]) GRU_STEP(x[11])
    GRU_STEP(x[12]) GRU_STEP(x[13]) GRU_STEP(x[14]) GRU_STEP(x[15])

    GRU_STEP(BC16(msum, 0))  GRU_STEP(BC16(msum, 1))
    GRU_STEP(BC16(msum, 2))  GRU_STEP(BC16(msum, 3))
    GRU_STEP(BC16(msum, 4))  GRU_STEP(BC16(msum, 5))
    GRU_STEP(BC16(msum, 6))  GRU_STEP(BC16(msum, 7))
    GRU_STEP(BC16(msum, 8))  GRU_STEP(BC16(msum, 9))
    GRU_STEP(BC16(msum, 10)) GRU_STEP(BC16(msum, 11))
    GRU_STEP(BC16(msum, 12)) GRU_STEP(BC16(msum, 13))
    GRU_STEP(BC16(msum, 14)) GRU_STEP(BC16(msum, 15))

#undef GRU_STEP
#undef DSTEP

    hid[node*16 + j] = hn;   // in-place safe: pointwise per node
}

// ---------------- K5: readout ----------------
__global__ void __launch_bounds__(256) k_readout(
        const float* __restrict__ hid, const float* __restrict__ hid0,
        const float* __restrict__ Wri, const float* __restrict__ bri,
        const float* __restrict__ Wrj, const float* __restrict__ brj,
        float* __restrict__ out)
{
    int n = blockIdx.x * 256 + threadIdx.x;
    float val = 0.0f;
    if (n < N_NODES) {
        const float4* h4 = (const float4*)(hid + n * 16);
        const float4* g4 = (const float4*)(hid0 + n * 16);
        float iv = bri[0];
        float jv = brj[0];
#pragma unroll
        for (int g = 0; g < 4; ++g) {
            float4 h  = h4[g];
            float4 h0 = g4[g];
            iv = fmaf(h.x,  Wri[g*4+0], iv);  iv = fmaf(h.y,  Wri[g*4+1], iv);
            iv = fmaf(h.z,  Wri[g*4+2], iv);  iv = fmaf(h.w,  Wri[g*4+3], iv);
            iv = fmaf(h0.x, Wri[16+g*4+0], iv); iv = fmaf(h0.y, Wri[16+g*4+1], iv);
            iv = fmaf(h0.z, Wri[16+g*4+2], iv); iv = fmaf(h0.w, Wri[16+g*4+3], iv);
            jv = fmaf(h.x,  Wrj[g*4+0], jv);  jv = fmaf(h.y,  Wrj[g*4+1], jv);
            jv = fmaf(h.z,  Wrj[g*4+2], jv);  jv = fmaf(h.w,  Wrj[g*4+3], jv);
        }
        val = iv * jv;
    }
#pragma unroll
    for (int off = 32; off > 0; off >>= 1)
        val += __shfl_xor(val, off, 64);
    __shared__ float wsum[4];
    int w = threadIdx.x >> 6;
    if ((threadIdx.x & 63) == 0) wsum[w] = val;
    __syncthreads();
    if (threadIdx.x == 0)
        atomicAdd(out, wsum[0] + wsum[1] + wsum[2] + wsum[3]);
}

// ---------------- launch ----------------
extern "C" void kernel_launch(void* const* d_in, const int* in_sizes, int n_in,
                              void* d_out, int out_size, void* d_ws, size_t ws_size,
                              hipStream_t stream)
{
    const float* node_features = (const float*)d_in[0];
    const float* edge_features = (const float*)d_in[1];
    const float* W_init = (const float*)d_in[2];
    const float* b_init = (const float*)d_in[3];
    const float* W_edge = (const float*)d_in[4];
    const float* b_edge = (const float*)d_in[5];
    const float* Wi_gru = (const float*)d_in[6];
    const float* Wh_gru = (const float*)d_in[7];
    const float* bi_gru = (const float*)d_in[8];
    const float* bh_gru = (const float*)d_in[9];
    const float* W_ri = (const float*)d_in[10];
    const float* b_ri = (const float*)d_in[11];
    const float* W_rj = (const float*)d_in[12];
    const float* b_rj = (const float*)d_in[13];
    const int* receivers = (const int*)d_in[14];
    const int* senders   = (const int*)d_in[15];
    float* out = (float*)d_out;

    // workspace carve
    float* fb      = (float*)d_ws;
    float* hidden0 = fb;                    // 400000
    float* hidA    = fb + 400000;           // 400000 (in-place GRU)
    float* emsg    = fb + 800000;           // 6400000 (E*16)
    int* ib    = (int*)(fb + 7200000);
    int* cnt_s = ib;                        // 25024
    int* cnt_r = ib + 25024;                // 25024
    int* srow  = ib + 50048;                // 25024
    int* rrow  = ib + 75072;                // 25024
    int* scur  = ib + 100096;               // 25024
    int* rcur  = ib + 125120;               // 25024
    int* eids  = ib + 150144;               // 400000
    int* gpos  = ib + 550144;               // 400000 -> ints end @ 950144
    float* efp = fb + 8150144;              // 6400000 (E*16) — fits, proven R4

    dim3 b256(256);
    int grid_n16 = (N_NODES * 16 + 255) / 256;   // 1563
    int grid_e   = (N_EDGES + 255) / 256;        // 1563
    int grid_s   = (N_NODES * 64 + 255) / 256;   // 6250 (one wave per sender)
    int grid_n   = (N_NODES + 255) / 256;        // 98

    k_init<<<grid_n16, b256, 0, stream>>>(node_features, W_init, b_init,
                                          hidden0, hidA, cnt_s, cnt_r);
    k_hist<<<grid_e, b256, 0, stream>>>(senders, receivers, cnt_s, cnt_r);
    k_scan<<<2, 1024, 0, stream>>>(cnt_s, cnt_r, srow, scur, rrow, rcur, out);
    k_scatter<<<grid_e, b256, 0, stream>>>(senders, receivers, scur, rcur,
                                           eids, gpos, edge_features, efp);

    for (int it = 0; it < 3; ++it) {
        k_msg<<<grid_s, b256, 0, stream>>>(hidA, efp, W_edge, b_edge, srow, emsg);
        k_gru<<<grid_n16, b256, 0, stream>>>(hidA, emsg, rrow, gpos,
                                             Wi_gru, Wh_gru, bi_gru, bh_gru);
    }

    k_readout<<<grid_n, b256, 0, stream>>>(hidA, hidden0, W_ri, b_ri, W_rj, b_rj, out);
}

// Round 6
// 566.868 us; speedup vs baseline: 1.2779x; 1.2779x over previous
//
#include <hip/hip_runtime.h>

#define N_NODES 25000
#define N_EDGES 400000

// ---------------- fast transcendentals (fp32, ~2ulp) ----------------
__device__ __forceinline__ float fast_sigmoid(float x) {
    return __builtin_amdgcn_rcpf(1.0f + __expf(-x));
}
__device__ __forceinline__ float fast_tanh(float x) {
    return 1.0f - 2.0f * __builtin_amdgcn_rcpf(__expf(2.0f * x) + 1.0f);
}

// XOR-type (self-inverse) DPP ops within 16-lane rows (verified R5: absmax 0):
//   0xB1 = quad_perm [1,0,3,2] (j^1), 0x4E = quad_perm [2,3,0,1] (j^2),
//   0x141 = row_half_mirror (j^7),   0x128 = row_ror:8 (j^8)
#define DPPF(x, ctrl) __int_as_float(__builtin_amdgcn_update_dpp( \
        __float_as_int(x), __float_as_int(x), (ctrl), 0xF, 0xF, false))

// Broadcast lane l (0..15) of the 16-lane group to all 16 (ds_swizzle, or-mask)
#define BC16(x, l) __int_as_float(__builtin_amdgcn_ds_swizzle(__float_as_int(x), ((l) << 5) | 0x10))

// ---------------- K1: hidden0 = nf @ W_init + b_init ; copy; zero cnts --------
__global__ void __launch_bounds__(256) k_init(
        const float* __restrict__ nf, const float* __restrict__ Wini,
        const float* __restrict__ bini,
        float* __restrict__ hidden0, float* __restrict__ hid,
        int* __restrict__ cnt_s, int* __restrict__ cnt_r)
{
    int gtid = blockIdx.x * 256 + threadIdx.x;
    if (gtid <= N_NODES) { cnt_s[gtid] = 0; cnt_r[gtid] = 0; }
    int node = gtid >> 4;
    int j = gtid & 15;
    if (node >= N_NODES) return;

    const float4* nf4 = (const float4*)(nf + node * 32);
    float acc = bini[j];
#pragma unroll
    for (int g = 0; g < 8; ++g) {
        float4 v = nf4[g];
        acc = fmaf(v.x, Wini[(g*4+0)*16 + j], acc);
        acc = fmaf(v.y, Wini[(g*4+1)*16 + j], acc);
        acc = fmaf(v.z, Wini[(g*4+2)*16 + j], acc);
        acc = fmaf(v.w, Wini[(g*4+3)*16 + j], acc);
    }
    hidden0[node*16 + j] = acc;
    hid[node*16 + j] = acc;
}

// ---------------- CSR build ----------------
__global__ void __launch_bounds__(256) k_hist(const int* __restrict__ send,
        const int* __restrict__ recv,
        int* __restrict__ cnt_s, int* __restrict__ cnt_r)
{
    int e = blockIdx.x * 256 + threadIdx.x;
    if (e < N_EDGES) {
        atomicAdd(&cnt_s[send[e]], 1);
        atomicAdd(&cnt_r[recv[e]], 1);
    }
}

// grid=2: block 0 scans sender counts, block 1 scans receiver counts
__global__ void __launch_bounds__(1024) k_scan(
        const int* __restrict__ cnt_s, const int* __restrict__ cnt_r,
        int* __restrict__ srow, int* __restrict__ scur,
        int* __restrict__ rrow, int* __restrict__ rcur,
        float* __restrict__ out)
{
    const int* cnt = (blockIdx.x == 0) ? cnt_s : cnt_r;
    int* row = (blockIdx.x == 0) ? srow : rrow;
    int* cur = (blockIdx.x == 0) ? scur : rcur;

    __shared__ int sums[1024];
    int t = threadIdx.x;
    const int CH = (N_NODES + 1023) / 1024 + 1;   // 25 -> covers 25600
    int base = t * CH;
    int s = 0;
    for (int i = 0; i < CH; ++i) {
        int idx = base + i;
        if (idx < N_NODES) s += cnt[idx];
    }
    sums[t] = s;
    __syncthreads();
    for (int off = 1; off < 1024; off <<= 1) {
        int add = (t >= off) ? sums[t - off] : 0;
        __syncthreads();
        sums[t] += add;
        __syncthreads();
    }
    int run = sums[t] - s;
    for (int i = 0; i < CH; ++i) {
        int idx = base + i;
        if (idx < N_NODES) {
            row[idx] = run;
            cur[idx] = run;
            run += cnt[idx];
        }
    }
    if (t == 0) {
        row[N_NODES] = N_EDGES;
        if (blockIdx.x == 0) out[0] = 0.0f;
    }
}

// eids[sp]=e ; gpos[rp]=sp  (ints only — no scattered 64B stores here)
__global__ void __launch_bounds__(256) k_scatter(const int* __restrict__ send,
        const int* __restrict__ recv,
        int* __restrict__ scur, int* __restrict__ rcur,
        int* __restrict__ eids, int* __restrict__ gpos)
{
    int e = blockIdx.x * 256 + threadIdx.x;
    if (e < N_EDGES) {
        int s = send[e];
        int r = recv[e];
        int sp = atomicAdd(&scur[s], 1);
        int rp = atomicAdd(&rcur[r], 1);
        eids[sp] = e;
        gpos[rp] = sp;
    }
}

// efp[pos,:] = ef[eids[pos],:]  — random float4 reads, sequential writes
__global__ void __launch_bounds__(256) k_permute(const float* __restrict__ ef,
        const int* __restrict__ eids, float* __restrict__ efp)
{
    int gtid = blockIdx.x * 256 + threadIdx.x;
    int pos = gtid >> 2;
    int c = gtid & 3;
    if (pos < N_EDGES)
        ((float4*)efp)[(size_t)pos*4 + c] =
            ((const float4*)ef)[(size_t)eids[pos]*4 + c];
}

// ---------------- per-sender q computation helper ----------------
__device__ __forceinline__ void load_q(const float* __restrict__ hid, int s, int m,
        const float* __restrict__ We, const float* __restrict__ be,
        float* __restrict__ q, float& qb)
{
    float h[16];
    {
        const float4* h4 = (const float4*)(hid + s*16);
        float4 a = h4[0], b = h4[1], c = h4[2], d = h4[3];
        h[0]=a.x;  h[1]=a.y;  h[2]=a.z;  h[3]=a.w;
        h[4]=b.x;  h[5]=b.y;  h[6]=b.z;  h[7]=b.w;
        h[8]=c.x;  h[9]=c.y;  h[10]=c.z; h[11]=c.w;
        h[12]=d.x; h[13]=d.y; h[14]=d.z; h[15]=d.w;
    }
#pragma unroll
    for (int f = 0; f < 16; ++f) {
        const float4* wf = (const float4*)(We + f*256 + m*16);
        float4 a = wf[0], b = wf[1], c = wf[2], d = wf[3];
        float acc;
        acc  = a.x*h[0]  + a.y*h[1]  + a.z*h[2]  + a.w*h[3];
        acc += b.x*h[4]  + b.y*h[5]  + b.z*h[6]  + b.w*h[7];
        acc += c.x*h[8]  + c.y*h[9]  + c.z*h[10] + c.w*h[11];
        acc += d.x*h[12] + d.y*h[13] + d.z*h[14] + d.w*h[15];
        q[f] = acc;
    }
    {
        const float4* bf = (const float4*)(be + m*16);
        float4 a = bf[0], b = bf[1], c = bf[2], d = bf[3];
        qb  = a.x*h[0]  + a.y*h[1]  + a.z*h[2]  + a.w*h[3];
        qb += b.x*h[4]  + b.y*h[5]  + b.z*h[6]  + b.w*h[7];
        qb += c.x*h[8]  + c.y*h[9]  + c.z*h[10] + c.w*h[11];
        qb += d.x*h[12] + d.y*h[13] + d.z*h[14] + d.w*h[15];
    }
}

__device__ __forceinline__ float edge_dot(float4 e0, float4 e1, float4 e2, float4 e3,
        const float* __restrict__ q, float qb)
{
    float a = qb;
    a = fmaf(e0.x, q[0],  a);
    a = fmaf(e0.y, q[1],  a);
    a = fmaf(e0.z, q[2],  a);
    a = fmaf(e0.w, q[3],  a);
    a = fmaf(e1.x, q[4],  a);
    a = fmaf(e1.y, q[5],  a);
    a = fmaf(e1.z, q[6],  a);
    a = fmaf(e1.w, q[7],  a);
    a = fmaf(e2.x, q[8],  a);
    a = fmaf(e2.y, q[9],  a);
    a = fmaf(e2.z, q[10], a);
    a = fmaf(e2.w, q[11], a);
    a = fmaf(e3.x, q[12], a);
    a = fmaf(e3.y, q[13], a);
    a = fmaf(e3.z, q[14], a);
    a = fmaf(e3.w, q[15], a);
    return a;
}

// ---------------- K3: messages, 16 lanes/sender, 4-edge manual batches ------
// All 16 float4 loads of a batch are issued into named regs before first use
// -> ~16 loads in flight per lane (MLP fix for the 37cyc/instr chaining).
__global__ void __launch_bounds__(256, 4) k_msg(
        const float* __restrict__ hid, const float* __restrict__ efp,
        const float* __restrict__ We, const float* __restrict__ be,
        const int* __restrict__ srow, float* __restrict__ emsg)
{
    int gtid = blockIdx.x * 256 + threadIdx.x;
    int s = gtid >> 4;
    int m = gtid & 15;
    if (s >= N_NODES) return;

    float q[16], qb;
    load_q(hid, s, m, We, be, q, qb);

    int beg = srow[s];
    int end = srow[s + 1];
    int i = beg;
    for (; i + 3 < end; i += 4) {
        const float4* p0 = (const float4*)(efp + (size_t)(i+0)*16);
        const float4* p1 = (const float4*)(efp + (size_t)(i+1)*16);
        const float4* p2 = (const float4*)(efp + (size_t)(i+2)*16);
        const float4* p3 = (const float4*)(efp + (size_t)(i+3)*16);
        float4 a0=p0[0], a1=p0[1], a2=p0[2], a3=p0[3];
        float4 b0=p1[0], b1=p1[1], b2=p1[2], b3=p1[3];
        float4 c0=p2[0], c1=p2[1], c2=p2[2], c3=p2[3];
        float4 d0=p3[0], d1=p3[1], d2=p3[2], d3=p3[3];
        float r0 = edge_dot(a0, a1, a2, a3, q, qb);
        float r1 = edge_dot(b0, b1, b2, b3, q, qb);
        float r2 = edge_dot(c0, c1, c2, c3, q, qb);
        float r3 = edge_dot(d0, d1, d2, d3, q, qb);
        emsg[(size_t)(i+0)*16 + m] = r0;
        emsg[(size_t)(i+1)*16 + m] = r1;
        emsg[(size_t)(i+2)*16 + m] = r2;
        emsg[(size_t)(i+3)*16 + m] = r3;
    }
    for (; i < end; ++i) {
        const float4* e4 = (const float4*)(efp + (size_t)i*16);
        float4 e0 = e4[0], e1 = e4[1], e2 = e4[2], e3 = e4[3];
        emsg[(size_t)i*16 + m] = edge_dot(e0, e1, e2, e3, q, qb);
    }
}

// ---------------- K4: gather segment-sum + GRU (T=32), TWO nodes per group --
// 16-lane group handles nodes nA=2g, nB=2g+1: weights shared, two independent
// recurrence chains interleaved (ILP=2 on the serial DPP/FMA chain), gathers
// 8 loads in flight.
__global__ void __launch_bounds__(256, 4) k_gru(
        float* __restrict__ hid, const float* __restrict__ emsg,
        const int* __restrict__ rrow, const int* __restrict__ gpos,
        const float* __restrict__ Wi, const float* __restrict__ Wh,
        const float* __restrict__ bi, const float* __restrict__ bh)
{
    int gtid = blockIdx.x * 256 + threadIdx.x;
    int grp = gtid >> 4;
    int j = gtid & 15;
    if (grp >= N_NODES / 2) return;     // 25000 even -> 12500 full pairs
    int nA = grp * 2;
    int nB = nA + 1;

    // prefix-XOR order of the DPP chain
    const int P[16] = {0,1,3,2,5,4,6,7,15,14,12,13,10,11,9,8};
    float Wz[16], Wr[16], Wc[16];
#pragma unroll
    for (int k = 0; k < 16; ++k) {
        int l = j ^ P[k];
        Wz[k] = Wh[l*48 + j];
        Wr[k] = Wh[l*48 + 16 + j];
        Wc[k] = Wh[l*48 + 32 + j];
    }
    float Wiz = Wi[j], Wir = Wi[16+j], Wih = Wi[32+j];
    float cz   = bi[j] + bh[j];
    float cr   = bi[16+j] + bh[16+j];
    float bih_ = bi[32+j];
    float bhh_ = bh[32+j];

    // segment sums for both nodes, interleaved 4-wide (8 gathers in flight)
    float msA = 0.0f, msB = 0.0f;
    {
        int pA = rrow[nA], eA = rrow[nA+1];
        int pB = rrow[nB], eB = rrow[nB+1];
        while (pA + 3 < eA && pB + 3 < eB) {
            int a0=gpos[pA], a1=gpos[pA+1], a2=gpos[pA+2], a3=gpos[pA+3];
            int b0=gpos[pB], b1=gpos[pB+1], b2=gpos[pB+2], b3=gpos[pB+3];
            float va0=emsg[(size_t)a0*16+j], va1=emsg[(size_t)a1*16+j];
            float va2=emsg[(size_t)a2*16+j], va3=emsg[(size_t)a3*16+j];
            float vb0=emsg[(size_t)b0*16+j], vb1=emsg[(size_t)b1*16+j];
            float vb2=emsg[(size_t)b2*16+j], vb3=emsg[(size_t)b3*16+j];
            msA += (va0+va1)+(va2+va3);
            msB += (vb0+vb1)+(vb2+vb3);
            pA += 4; pB += 4;
        }
        for (; pA + 3 < eA; pA += 4) {
            int a0=gpos[pA], a1=gpos[pA+1], a2=gpos[pA+2], a3=gpos[pA+3];
            float v0=emsg[(size_t)a0*16+j], v1=emsg[(size_t)a1*16+j];
            float v2=emsg[(size_t)a2*16+j], v3=emsg[(size_t)a3*16+j];
            msA += (v0+v1)+(v2+v3);
        }
        for (; pA < eA; ++pA) msA += emsg[(size_t)gpos[pA]*16+j];
        for (; pB + 3 < eB; pB += 4) {
            int b0=gpos[pB], b1=gpos[pB+1], b2=gpos[pB+2], b3=gpos[pB+3];
            float v0=emsg[(size_t)b0*16+j], v1=emsg[(size_t)b1*16+j];
            float v2=emsg[(size_t)b2*16+j], v3=emsg[(size_t)b3*16+j];
            msB += (v0+v1)+(v2+v3);
        }
        for (; pB < eB; ++pB) msB += emsg[(size_t)gpos[pB]*16+j];
    }

    float xA[16], xB[16];
    {
        const float4* a4 = (const float4*)(hid + nA * 16);
        const float4* b4 = (const float4*)(hid + nB * 16);
#pragma unroll
        for (int g = 0; g < 4; ++g) {
            float4 v = a4[g];
            xA[g*4+0]=v.x; xA[g*4+1]=v.y; xA[g*4+2]=v.z; xA[g*4+3]=v.w;
        }
#pragma unroll
        for (int g = 0; g < 4; ++g) {
            float4 v = b4[g];
            xB[g*4+0]=v.x; xB[g*4+1]=v.y; xB[g*4+2]=v.z; xB[g*4+3]=v.w;
        }
    }

    float hnA = 0.0f, hnB = 0.0f;

#define DSTEP2(k, ctrl) { vA = DPPF(vA, ctrl); vB = DPPF(vB, ctrl); \
        azA = fmaf(vA, Wz[k], azA); arA = fmaf(vA, Wr[k], arA); acA = fmaf(vA, Wc[k], acA); \
        azB = fmaf(vB, Wz[k], azB); arB = fmaf(vB, Wr[k], arB); acB = fmaf(vB, Wc[k], acB); }

#define GRU_STEP2(XA, XB) { float xa = (XA), xb = (XB); \
        float azA = fmaf(xa, Wiz, cz), arA = fmaf(xa, Wir, cr), acA = bhh_; \
        float azB = fmaf(xb, Wiz, cz), arB = fmaf(xb, Wir, cr), acB = bhh_; \
        float vA = hnA, vB = hnB; \
        azA = fmaf(vA, Wz[0], azA); arA = fmaf(vA, Wr[0], arA); acA = fmaf(vA, Wc[0], acA); \
        azB = fmaf(vB, Wz[0], azB); arB = fmaf(vB, Wr[0], arB); acB = fmaf(vB, Wc[0], acB); \
        DSTEP2(1, 0xB1)  DSTEP2(2, 0x4E)  DSTEP2(3, 0xB1)  DSTEP2(4, 0x141) \
        DSTEP2(5, 0xB1)  DSTEP2(6, 0x4E)  DSTEP2(7, 0xB1)  DSTEP2(8, 0x128) \
        DSTEP2(9, 0xB1)  DSTEP2(10, 0x4E) DSTEP2(11, 0xB1) DSTEP2(12, 0x141) \
        DSTEP2(13, 0xB1) DSTEP2(14, 0x4E) DSTEP2(15, 0xB1) \
        float zA = fast_sigmoid(azA), rA = fast_sigmoid(arA); \
        float zB = fast_sigmoid(azB), rB = fast_sigmoid(arB); \
        float hcA = fast_tanh(fmaf(xa, Wih, bih_) + rA * acA); \
        float hcB = fast_tanh(fmaf(xb, Wih, bih_) + rB * acB); \
        hnA = fmaf(zA, hnA - hcA, hcA); \
        hnB = fmaf(zB, hnB - hcB, hcB); }

    GRU_STEP2(xA[0], xB[0])   GRU_STEP2(xA[1], xB[1])
    GRU_STEP2(xA[2], xB[2])   GRU_STEP2(xA[3], xB[3])
    GRU_STEP2(xA[4], xB[4])   GRU_STEP2(xA[5], xB[5])
    GRU_STEP2(xA[6], xB[6])   GRU_STEP2(xA[7], xB[7])
    GRU_STEP2(xA[8], xB[8])   GRU_STEP2(xA[9], xB[9])
    GRU_STEP2(xA[10], xB[10]) GRU_STEP2(xA[11], xB[11])
    GRU_STEP2(xA[12], xB[12]) GRU_STEP2(xA[13], xB[13])
    GRU_STEP2(xA[14], xB[14]) GRU_STEP2(xA[15], xB[15])

    GRU_STEP2(BC16(msA, 0),  BC16(msB, 0))   GRU_STEP2(BC16(msA, 1),  BC16(msB, 1))
    GRU_STEP2(BC16(msA, 2),  BC16(msB, 2))   GRU_STEP2(BC16(msA, 3),  BC16(msB, 3))
    GRU_STEP2(BC16(msA, 4),  BC16(msB, 4))   GRU_STEP2(BC16(msA, 5),  BC16(msB, 5))
    GRU_STEP2(BC16(msA, 6),  BC16(msB, 6))   GRU_STEP2(BC16(msA, 7),  BC16(msB, 7))
    GRU_STEP2(BC16(msA, 8),  BC16(msB, 8))   GRU_STEP2(BC16(msA, 9),  BC16(msB, 9))
    GRU_STEP2(BC16(msA, 10), BC16(msB, 10))  GRU_STEP2(BC16(msA, 11), BC16(msB, 11))
    GRU_STEP2(BC16(msA, 12), BC16(msB, 12))  GRU_STEP2(BC16(msA, 13), BC16(msB, 13))
    GRU_STEP2(BC16(msA, 14), BC16(msB, 14))  GRU_STEP2(BC16(msA, 15), BC16(msB, 15))

#undef GRU_STEP2
#undef DSTEP2

    hid[nA*16 + j] = hnA;
    hid[nB*16 + j] = hnB;
}

// ---------------- K5: readout ----------------
__global__ void __launch_bounds__(256) k_readout(
        const float* __restrict__ hid, const float* __restrict__ hid0,
        const float* __restrict__ Wri, const float* __restrict__ bri,
        const float* __restrict__ Wrj, const float* __restrict__ brj,
        float* __restrict__ out)
{
    int n = blockIdx.x * 256 + threadIdx.x;
    float val = 0.0f;
    if (n < N_NODES) {
        const float4* h4 = (const float4*)(hid + n * 16);
        const float4* g4 = (const float4*)(hid0 + n * 16);
        float iv = bri[0];
        float jv = brj[0];
#pragma unroll
        for (int g = 0; g < 4; ++g) {
            float4 h  = h4[g];
            float4 h0 = g4[g];
            iv = fmaf(h.x,  Wri[g*4+0], iv);  iv = fmaf(h.y,  Wri[g*4+1], iv);
            iv = fmaf(h.z,  Wri[g*4+2], iv);  iv = fmaf(h.w,  Wri[g*4+3], iv);
            iv = fmaf(h0.x, Wri[16+g*4+0], iv); iv = fmaf(h0.y, Wri[16+g*4+1], iv);
            iv = fmaf(h0.z, Wri[16+g*4+2], iv); iv = fmaf(h0.w, Wri[16+g*4+3], iv);
            jv = fmaf(h.x,  Wrj[g*4+0], jv);  jv = fmaf(h.y,  Wrj[g*4+1], jv);
            jv = fmaf(h.z,  Wrj[g*4+2], jv);  jv = fmaf(h.w,  Wrj[g*4+3], jv);
        }
        val = iv * jv;
    }
#pragma unroll
    for (int off = 32; off > 0; off >>= 1)
        val += __shfl_xor(val, off, 64);
    __shared__ float wsum[4];
    int w = threadIdx.x >> 6;
    if ((threadIdx.x & 63) == 0) wsum[w] = val;
    __syncthreads();
    if (threadIdx.x == 0)
        atomicAdd(out, wsum[0] + wsum[1] + wsum[2] + wsum[3]);
}

// ---------------- launch ----------------
extern "C" void kernel_launch(void* const* d_in, const int* in_sizes, int n_in,
                              void* d_out, int out_size, void* d_ws, size_t ws_size,
                              hipStream_t stream)
{
    const float* node_features = (const float*)d_in[0];
    const float* edge_features = (const float*)d_in[1];
    const float* W_init = (const float*)d_in[2];
    const float* b_init = (const float*)d_in[3];
    const float* W_edge = (const float*)d_in[4];
    const float* b_edge = (const float*)d_in[5];
    const float* Wi_gru = (const float*)d_in[6];
    const float* Wh_gru = (const float*)d_in[7];
    const float* bi_gru = (const float*)d_in[8];
    const float* bh_gru = (const float*)d_in[9];
    const float* W_ri = (const float*)d_in[10];
    const float* b_ri = (const float*)d_in[11];
    const float* W_rj = (const float*)d_in[12];
    const float* b_rj = (const float*)d_in[13];
    const int* receivers = (const int*)d_in[14];
    const int* senders   = (const int*)d_in[15];
    float* out = (float*)d_out;

    // workspace carve (efp high region proven to fit in R4/R5)
    float* fb      = (float*)d_ws;
    float* hidden0 = fb;                    // 400000
    float* hidA    = fb + 400000;           // 400000 (in-place GRU)
    float* emsg    = fb + 800000;           // 6400000 (E*16)
    int* ib    = (int*)(fb + 7200000);
    int* cnt_s = ib;                        // 25024
    int* cnt_r = ib + 25024;                // 25024
    int* srow  = ib + 50048;                // 25024
    int* rrow  = ib + 75072;                // 25024
    int* scur  = ib + 100096;               // 25024
    int* rcur  = ib + 125120;               // 25024
    int* eids  = ib + 150144;               // 400000
    int* gpos  = ib + 550144;               // 400000 -> ints end @ 950144
    float* efp = fb + 8150144;              // 6400000 (E*16)

    dim3 b256(256);
    int grid_n16 = (N_NODES * 16 + 255) / 256;   // 1563
    int grid_e   = (N_EDGES + 255) / 256;        // 1563
    int grid_e4  = (N_EDGES * 4 + 255) / 256;    // 6250
    int grid_g   = ((N_NODES/2) * 16 + 255) / 256; // 782 (2 nodes per group)
    int grid_n   = (N_NODES + 255) / 256;        // 98

    k_init<<<grid_n16, b256, 0, stream>>>(node_features, W_init, b_init,
                                          hidden0, hidA, cnt_s, cnt_r);
    k_hist<<<grid_e, b256, 0, stream>>>(senders, receivers, cnt_s, cnt_r);
    k_scan<<<2, 1024, 0, stream>>>(cnt_s, cnt_r, srow, scur, rrow, rcur, out);
    k_scatter<<<grid_e, b256, 0, stream>>>(senders, receivers, scur, rcur,
                                           eids, gpos);
    k_permute<<<grid_e4, b256, 0, stream>>>(edge_features, eids, efp);

    for (int it = 0; it < 3; ++it) {
        k_msg<<<grid_n16, b256, 0, stream>>>(hidA, efp, W_edge, b_edge, srow, emsg);
        k_gru<<<grid_g, b256, 0, stream>>>(hidA, emsg, rrow, gpos,
                                           Wi_gru, Wh_gru, bi_gru, bh_gru);
    }

    k_readout<<<grid_n, b256, 0, stream>>>(hidA, hidden0, W_ri, b_ri, W_rj, b_rj, out);
}

// Round 7
// 536.452 us; speedup vs baseline: 1.3503x; 1.0567x over previous
//
#include <hip/hip_runtime.h>

#define N_NODES 25000
#define N_EDGES 400000

// ---------------- fast transcendentals (fp32, ~2ulp) ----------------
__device__ __forceinline__ float fast_sigmoid(float x) {
    return __builtin_amdgcn_rcpf(1.0f + __expf(-x));
}
__device__ __forceinline__ float fast_tanh(float x) {
    return 1.0f - 2.0f * __builtin_amdgcn_rcpf(__expf(2.0f * x) + 1.0f);
}

// XOR-type (self-inverse) DPP ops within 16-lane rows (verified R5/R6):
//   0xB1 = quad_perm [1,0,3,2] (j^1), 0x4E = quad_perm [2,3,0,1] (j^2),
//   0x141 = row_half_mirror (j^7),   0x128 = row_ror:8 (j^8)
#define DPPF(x, ctrl) __int_as_float(__builtin_amdgcn_update_dpp( \
        __float_as_int(x), __float_as_int(x), (ctrl), 0xF, 0xF, false))

// Broadcast lane l (0..15) of the 16-lane group to all 16 (ds_swizzle or-mask;
// applies per 32-lane half: src = (lane&0x10)|l). Verified R3-R6 (absmax 0).
#define BC16(x, l) __int_as_float(__builtin_amdgcn_ds_swizzle(__float_as_int(x), ((l) << 5) | 0x10))

// ---------------- K1: hidden0 = nf @ W_init + b_init ; copy; zero cnts --------
__global__ void __launch_bounds__(256) k_init(
        const float* __restrict__ nf, const float* __restrict__ Wini,
        const float* __restrict__ bini,
        float* __restrict__ hidden0, float* __restrict__ hid,
        int* __restrict__ cnt_s, int* __restrict__ cnt_r)
{
    int gtid = blockIdx.x * 256 + threadIdx.x;
    if (gtid <= N_NODES) { cnt_s[gtid] = 0; cnt_r[gtid] = 0; }
    int node = gtid >> 4;
    int j = gtid & 15;
    if (node >= N_NODES) return;

    const float4* nf4 = (const float4*)(nf + node * 32);
    float acc = bini[j];
#pragma unroll
    for (int g = 0; g < 8; ++g) {
        float4 v = nf4[g];
        acc = fmaf(v.x, Wini[(g*4+0)*16 + j], acc);
        acc = fmaf(v.y, Wini[(g*4+1)*16 + j], acc);
        acc = fmaf(v.z, Wini[(g*4+2)*16 + j], acc);
        acc = fmaf(v.w, Wini[(g*4+3)*16 + j], acc);
    }
    hidden0[node*16 + j] = acc;
    hid[node*16 + j] = acc;
}

// ---------------- CSR build ----------------
__global__ void __launch_bounds__(256) k_hist(const int* __restrict__ send,
        const int* __restrict__ recv,
        int* __restrict__ cnt_s, int* __restrict__ cnt_r)
{
    int e = blockIdx.x * 256 + threadIdx.x;
    if (e < N_EDGES) {
        atomicAdd(&cnt_s[send[e]], 1);
        atomicAdd(&cnt_r[recv[e]], 1);
    }
}

// grid=2: block 0 scans sender counts, block 1 scans receiver counts
__global__ void __launch_bounds__(1024) k_scan(
        const int* __restrict__ cnt_s, const int* __restrict__ cnt_r,
        int* __restrict__ srow, int* __restrict__ scur,
        int* __restrict__ rrow, int* __restrict__ rcur,
        float* __restrict__ out)
{
    const int* cnt = (blockIdx.x == 0) ? cnt_s : cnt_r;
    int* row = (blockIdx.x == 0) ? srow : rrow;
    int* cur = (blockIdx.x == 0) ? scur : rcur;

    __shared__ int sums[1024];
    int t = threadIdx.x;
    const int CH = (N_NODES + 1023) / 1024 + 1;   // 25 -> covers 25600
    int base = t * CH;
    int s = 0;
    for (int i = 0; i < CH; ++i) {
        int idx = base + i;
        if (idx < N_NODES) s += cnt[idx];
    }
    sums[t] = s;
    __syncthreads();
    for (int off = 1; off < 1024; off <<= 1) {
        int add = (t >= off) ? sums[t - off] : 0;
        __syncthreads();
        sums[t] += add;
        __syncthreads();
    }
    int run = sums[t] - s;
    for (int i = 0; i < CH; ++i) {
        int idx = base + i;
        if (idx < N_NODES) {
            row[idx] = run;
            cur[idx] = run;
            run += cnt[idx];
        }
    }
    if (t == 0) {
        row[N_NODES] = N_EDGES;
        if (blockIdx.x == 0) out[0] = 0.0f;
    }
}

// eids[sp]=e ; gpos[rp]=sp  (ints only)
__global__ void __launch_bounds__(256) k_scatter(const int* __restrict__ send,
        const int* __restrict__ recv,
        int* __restrict__ scur, int* __restrict__ rcur,
        int* __restrict__ eids, int* __restrict__ gpos)
{
    int e = blockIdx.x * 256 + threadIdx.x;
    if (e < N_EDGES) {
        int s = send[e];
        int r = recv[e];
        int sp = atomicAdd(&scur[s], 1);
        int rp = atomicAdd(&rcur[r], 1);
        eids[sp] = e;
        gpos[rp] = sp;
    }
}

// efp[pos,:] = ef[eids[pos],:]  — random float4 reads, sequential writes
__global__ void __launch_bounds__(256) k_permute(const float* __restrict__ ef,
        const int* __restrict__ eids, float* __restrict__ efp)
{
    int gtid = blockIdx.x * 256 + threadIdx.x;
    int pos = gtid >> 2;
    int c = gtid & 3;
    if (pos < N_EDGES)
        ((float4*)efp)[(size_t)pos*4 + c] =
            ((const float4*)ef)[(size_t)eids[pos]*4 + c];
}

// ---------------- per-sender q computation helper ----------------
__device__ __forceinline__ void load_q(const float* __restrict__ hid, int s, int m,
        const float* __restrict__ We, const float* __restrict__ be,
        float* __restrict__ q, float& qb)
{
    float h[16];
    {
        const float4* h4 = (const float4*)(hid + s*16);
        float4 a = h4[0], b = h4[1], c = h4[2], d = h4[3];
        h[0]=a.x;  h[1]=a.y;  h[2]=a.z;  h[3]=a.w;
        h[4]=b.x;  h[5]=b.y;  h[6]=b.z;  h[7]=b.w;
        h[8]=c.x;  h[9]=c.y;  h[10]=c.z; h[11]=c.w;
        h[12]=d.x; h[13]=d.y; h[14]=d.z; h[15]=d.w;
    }
#pragma unroll
    for (int f = 0; f < 16; ++f) {
        const float4* wf = (const float4*)(We + f*256 + m*16);
        float4 a = wf[0], b = wf[1], c = wf[2], d = wf[3];
        float acc;
        acc  = a.x*h[0]  + a.y*h[1]  + a.z*h[2]  + a.w*h[3];
        acc += b.x*h[4]  + b.y*h[5]  + b.z*h[6]  + b.w*h[7];
        acc += c.x*h[8]  + c.y*h[9]  + c.z*h[10] + c.w*h[11];
        acc += d.x*h[12] + d.y*h[13] + d.z*h[14] + d.w*h[15];
        q[f] = acc;
    }
    {
        const float4* bf = (const float4*)(be + m*16);
        float4 a = bf[0], b = bf[1], c = bf[2], d = bf[3];
        qb  = a.x*h[0]  + a.y*h[1]  + a.z*h[2]  + a.w*h[3];
        qb += b.x*h[4]  + b.y*h[5]  + b.z*h[6]  + b.w*h[7];
        qb += c.x*h[8]  + c.y*h[9]  + c.z*h[10] + c.w*h[11];
        qb += d.x*h[12] + d.y*h[13] + d.z*h[14] + d.w*h[15];
    }
}

// ---------------- K3: messages, lane-distributed ef + swizzle broadcast -----
// group = sender s, lane = msg dim m. Per 4-edge batch: ONE coalesced 256B
// load (lane l holds float4 #l of the 4-row block: row l>>2, feats 4(l&3));
// messages formed with ds_swizzle broadcasts against the lane-resident q.
__global__ void __launch_bounds__(256) k_msg(
        const float* __restrict__ hid, const float* __restrict__ efp,
        const float* __restrict__ We, const float* __restrict__ be,
        const int* __restrict__ srow, float* __restrict__ emsg)
{
    int gtid = blockIdx.x * 256 + threadIdx.x;
    int s = gtid >> 4;
    int m = gtid & 15;
    if (s >= N_NODES) return;

    float q[16], qb;
    load_q(hid, s, m, We, be, q, qb);

    int beg = srow[s];
    int end = srow[s + 1];
    int i = beg;

    // lane (4r+c) holds feats 4c..4c+3 of edge (i+r) in F.x..F.w
#define EMSG(r) ({ float acc = qb; \
        acc = fmaf(BC16(F.x, 4*(r)+0), q[0],  acc); \
        acc = fmaf(BC16(F.y, 4*(r)+0), q[1],  acc); \
        acc = fmaf(BC16(F.z, 4*(r)+0), q[2],  acc); \
        acc = fmaf(BC16(F.w, 4*(r)+0), q[3],  acc); \
        acc = fmaf(BC16(F.x, 4*(r)+1), q[4],  acc); \
        acc = fmaf(BC16(F.y, 4*(r)+1), q[5],  acc); \
        acc = fmaf(BC16(F.z, 4*(r)+1), q[6],  acc); \
        acc = fmaf(BC16(F.w, 4*(r)+1), q[7],  acc); \
        acc = fmaf(BC16(F.x, 4*(r)+2), q[8],  acc); \
        acc = fmaf(BC16(F.y, 4*(r)+2), q[9],  acc); \
        acc = fmaf(BC16(F.z, 4*(r)+2), q[10], acc); \
        acc = fmaf(BC16(F.w, 4*(r)+2), q[11], acc); \
        acc = fmaf(BC16(F.x, 4*(r)+3), q[12], acc); \
        acc = fmaf(BC16(F.y, 4*(r)+3), q[13], acc); \
        acc = fmaf(BC16(F.z, 4*(r)+3), q[14], acc); \
        acc = fmaf(BC16(F.w, 4*(r)+3), q[15], acc); \
        acc; })

    for (; i + 3 < end; i += 4) {
        float4 F = ((const float4*)efp)[(size_t)i*4 + m];
        float r0 = EMSG(0);
        float r1 = EMSG(1);
        float r2 = EMSG(2);
        float r3 = EMSG(3);
        emsg[(size_t)(i+0)*16 + m] = r0;
        emsg[(size_t)(i+1)*16 + m] = r1;
        emsg[(size_t)(i+2)*16 + m] = r2;
        emsg[(size_t)(i+3)*16 + m] = r3;
    }
#undef EMSG
    // remainder (<=3 edges): per-lane row loads (redundant but rare)
    for (; i < end; ++i) {
        const float4* e4 = (const float4*)(efp + (size_t)i*16);
        float4 e0 = e4[0], e1 = e4[1], e2 = e4[2], e3 = e4[3];
        float a = qb;
        a = fmaf(e0.x, q[0],  a); a = fmaf(e0.y, q[1],  a);
        a = fmaf(e0.z, q[2],  a); a = fmaf(e0.w, q[3],  a);
        a = fmaf(e1.x, q[4],  a); a = fmaf(e1.y, q[5],  a);
        a = fmaf(e1.z, q[6],  a); a = fmaf(e1.w, q[7],  a);
        a = fmaf(e2.x, q[8],  a); a = fmaf(e2.y, q[9],  a);
        a = fmaf(e2.z, q[10], a); a = fmaf(e2.w, q[11], a);
        a = fmaf(e3.x, q[12], a); a = fmaf(e3.y, q[13], a);
        a = fmaf(e3.z, q[14], a); a = fmaf(e3.w, q[15], a);
        emsg[(size_t)i*16 + m] = a;
    }
}

// ---------------- K3b: segment-sum gather — ONE WAVE PER RECEIVER ----------
// 25000 waves. 4 sub-groups of 16 lanes; sub handles edges p+sub stride 4;
// cross-sub reduction via shfl_xor(16/32); lanes 0-15 store the 64B row.
__global__ void __launch_bounds__(256) k_sum(
        const float* __restrict__ emsg, const int* __restrict__ rrow,
        const int* __restrict__ gpos, float* __restrict__ msum)
{
    int r = (blockIdx.x * 256 + threadIdx.x) >> 6;
    if (r >= N_NODES) return;
    int lane = threadIdx.x & 63;
    int j = lane & 15;
    int sub = lane >> 4;

    int beg = rrow[r];
    int end = rrow[r + 1];
    float acc = 0.0f;
    for (int p = beg + sub; p < end; p += 4)
        acc += emsg[(size_t)gpos[p]*16 + j];

    acc += __shfl_xor(acc, 16, 64);
    acc += __shfl_xor(acc, 32, 64);
    if (sub == 0) msum[r*16 + j] = acc;
}

// ---------------- K4: GRU (T=32), 1 node/group, no gather, in-place --------
__global__ void __launch_bounds__(256) k_gru(
        float* __restrict__ hid, const float* __restrict__ msum,
        const float* __restrict__ Wi, const float* __restrict__ Wh,
        const float* __restrict__ bi, const float* __restrict__ bh)
{
    int gtid = blockIdx.x * 256 + threadIdx.x;
    int node = gtid >> 4;
    int j = gtid & 15;
    if (node >= N_NODES) return;

    // prefix-XOR order of the DPP chain
    const int P[16] = {0,1,3,2,5,4,6,7,15,14,12,13,10,11,9,8};
    float Wz[16], Wr[16], Wc[16];
#pragma unroll
    for (int k = 0; k < 16; ++k) {
        int l = j ^ P[k];
        Wz[k] = Wh[l*48 + j];
        Wr[k] = Wh[l*48 + 16 + j];
        Wc[k] = Wh[l*48 + 32 + j];
    }
    float Wiz = Wi[j], Wir = Wi[16+j], Wih = Wi[32+j];
    float cz   = bi[j] + bh[j];
    float cr   = bi[16+j] + bh[16+j];
    float bih_ = bi[32+j];
    float bhh_ = bh[32+j];

    float ms = msum[node*16 + j];

    float x[16];
    {
        const float4* a4 = (const float4*)(hid + node * 16);
#pragma unroll
        for (int g = 0; g < 4; ++g) {
            float4 v = a4[g];
            x[g*4+0]=v.x; x[g*4+1]=v.y; x[g*4+2]=v.z; x[g*4+3]=v.w;
        }
    }

    float hn = 0.0f;

#define DSTEP(k, ctrl) { v = DPPF(v, ctrl); \
        az = fmaf(v, Wz[k], az); ar = fmaf(v, Wr[k], ar); ac = fmaf(v, Wc[k], ac); }

#define GRU_STEP(XV) { float xv = (XV); \
        float az = fmaf(xv, Wiz, cz); \
        float ar = fmaf(xv, Wir, cr); \
        float ac = bhh_; \
        float v = hn; \
        az = fmaf(v, Wz[0], az); \
        ar = fmaf(v, Wr[0], ar); \
        ac = fmaf(v, Wc[0], ac); \
        DSTEP(1, 0xB1)  DSTEP(2, 0x4E)  DSTEP(3, 0xB1)  DSTEP(4, 0x141) \
        DSTEP(5, 0xB1)  DSTEP(6, 0x4E)  DSTEP(7, 0xB1)  DSTEP(8, 0x128) \
        DSTEP(9, 0xB1)  DSTEP(10, 0x4E) DSTEP(11, 0xB1) DSTEP(12, 0x141) \
        DSTEP(13, 0xB1) DSTEP(14, 0x4E) DSTEP(15, 0xB1) \
        float zg  = fast_sigmoid(az); \
        float rg  = fast_sigmoid(ar); \
        float hc = fast_tanh(fmaf(xv, Wih, bih_) + rg * ac); \
        hn = fmaf(zg, hn - hc, hc); }

    GRU_STEP(x[0])  GRU_STEP(x[1])  GRU_STEP(x[2])  GRU_STEP(x[3])
    GRU_STEP(x[4])  GRU_STEP(x[5])  GRU_STEP(x[6])  GRU_STEP(x[7])
    GRU_STEP(x[8])  GRU_STEP(x[9])  GRU_STEP(x[10]) GRU_STEP(x[11])
    GRU_STEP(x[12]) GRU_STEP(x[13]) GRU_STEP(x[14]) GRU_STEP(x[15])

    GRU_STEP(BC16(ms, 0))  GRU_STEP(BC16(ms, 1))
    GRU_STEP(BC16(ms, 2))  GRU_STEP(BC16(ms, 3))
    GRU_STEP(BC16(ms, 4))  GRU_STEP(BC16(ms, 5))
    GRU_STEP(BC16(ms, 6))  GRU_STEP(BC16(ms, 7))
    GRU_STEP(BC16(ms, 8))  GRU_STEP(BC16(ms, 9))
    GRU_STEP(BC16(ms, 10)) GRU_STEP(BC16(ms, 11))
    GRU_STEP(BC16(ms, 12)) GRU_STEP(BC16(ms, 13))
    GRU_STEP(BC16(ms, 14)) GRU_STEP(BC16(ms, 15))

#undef GRU_STEP
#undef DSTEP

    hid[node*16 + j] = hn;   // in-place safe: pointwise per node
}

// ---------------- K5: readout ----------------
__global__ void __launch_bounds__(256) k_readout(
        const float* __restrict__ hid, const float* __restrict__ hid0,
        const float* __restrict__ Wri, const float* __restrict__ bri,
        const float* __restrict__ Wrj, const float* __restrict__ brj,
        float* __restrict__ out)
{
    int n = blockIdx.x * 256 + threadIdx.x;
    float val = 0.0f;
    if (n < N_NODES) {
        const float4* h4 = (const float4*)(hid + n * 16);
        const float4* g4 = (const float4*)(hid0 + n * 16);
        float iv = bri[0];
        float jv = brj[0];
#pragma unroll
        for (int g = 0; g < 4; ++g) {
            float4 h  = h4[g];
            float4 h0 = g4[g];
            iv = fmaf(h.x,  Wri[g*4+0], iv);  iv = fmaf(h.y,  Wri[g*4+1], iv);
            iv = fmaf(h.z,  Wri[g*4+2], iv);  iv = fmaf(h.w,  Wri[g*4+3], iv);
            iv = fmaf(h0.x, Wri[16+g*4+0], iv); iv = fmaf(h0.y, Wri[16+g*4+1], iv);
            iv = fmaf(h0.z, Wri[16+g*4+2], iv); iv = fmaf(h0.w, Wri[16+g*4+3], iv);
            jv = fmaf(h.x,  Wrj[g*4+0], jv);  jv = fmaf(h.y,  Wrj[g*4+1], jv);
            jv = fmaf(h.z,  Wrj[g*4+2], jv);  jv = fmaf(h.w,  Wrj[g*4+3], jv);
        }
        val = iv * jv;
    }
#pragma unroll
    for (int off = 32; off > 0; off >>= 1)
        val += __shfl_xor(val, off, 64);
    __shared__ float wsum[4];
    int w = threadIdx.x >> 6;
    if ((threadIdx.x & 63) == 0) wsum[w] = val;
    __syncthreads();
    if (threadIdx.x == 0)
        atomicAdd(out, wsum[0] + wsum[1] + wsum[2] + wsum[3]);
}

// ---------------- launch ----------------
extern "C" void kernel_launch(void* const* d_in, const int* in_sizes, int n_in,
                              void* d_out, int out_size, void* d_ws, size_t ws_size,
                              hipStream_t stream)
{
    const float* node_features = (const float*)d_in[0];
    const float* edge_features = (const float*)d_in[1];
    const float* W_init = (const float*)d_in[2];
    const float* b_init = (const float*)d_in[3];
    const float* W_edge = (const float*)d_in[4];
    const float* b_edge = (const float*)d_in[5];
    const float* Wi_gru = (const float*)d_in[6];
    const float* Wh_gru = (const float*)d_in[7];
    const float* bi_gru = (const float*)d_in[8];
    const float* bh_gru = (const float*)d_in[9];
    const float* W_ri = (const float*)d_in[10];
    const float* b_ri = (const float*)d_in[11];
    const float* W_rj = (const float*)d_in[12];
    const float* b_rj = (const float*)d_in[13];
    const int* receivers = (const int*)d_in[14];
    const int* senders   = (const int*)d_in[15];
    float* out = (float*)d_out;

    // workspace carve (58.2 MB total — proven to fit R4-R6)
    float* fb      = (float*)d_ws;
    float* hidden0 = fb;                    // 400000
    float* hidA    = fb + 400000;           // 400000 (in-place GRU)
    float* emsg    = fb + 800000;           // 6400000 (E*16)
    int* ib    = (int*)(fb + 7200000);
    int* cnt_s = ib;                        // 25024
    int* cnt_r = ib + 25024;                // 25024
    int* srow  = ib + 50048;                // 25024
    int* rrow  = ib + 75072;                // 25024
    int* scur  = ib + 100096;               // 25024
    int* rcur  = ib + 125120;               // 25024
    int* eids  = ib + 150144;               // 400000 (dead after k_permute)
    int* gpos  = ib + 550144;               // 400000
    float* msum = (float*)eids;             // reuse: written after eids' last read
    float* efp = fb + 8150144;              // 6400000 (E*16)

    dim3 b256(256);
    int grid_n16 = (N_NODES * 16 + 255) / 256;   // 1563
    int grid_e   = (N_EDGES + 255) / 256;        // 1563
    int grid_e4  = (N_EDGES * 4 + 255) / 256;    // 6250
    int grid_w   = (N_NODES * 64 + 255) / 256;   // 6250 (wave per receiver)
    int grid_n   = (N_NODES + 255) / 256;        // 98

    k_init<<<grid_n16, b256, 0, stream>>>(node_features, W_init, b_init,
                                          hidden0, hidA, cnt_s, cnt_r);
    k_hist<<<grid_e, b256, 0, stream>>>(senders, receivers, cnt_s, cnt_r);
    k_scan<<<2, 1024, 0, stream>>>(cnt_s, cnt_r, srow, scur, rrow, rcur, out);
    k_scatter<<<grid_e, b256, 0, stream>>>(senders, receivers, scur, rcur,
                                           eids, gpos);
    k_permute<<<grid_e4, b256, 0, stream>>>(edge_features, eids, efp);

    for (int it = 0; it < 3; ++it) {
        k_msg<<<grid_n16, b256, 0, stream>>>(hidA, efp, W_edge, b_edge, srow, emsg);
        k_sum<<<grid_w, b256, 0, stream>>>(emsg, rrow, gpos, msum);
        k_gru<<<grid_n16, b256, 0, stream>>>(hidA, msum, Wi_gru, Wh_gru,
                                             bi_gru, bh_gru);
    }

    k_readout<<<grid_n, b256, 0, stream>>>(hidA, hidden0, W_ri, b_ri, W_rj, b_rj, out);
}